// Round 3
// baseline (563.524 us; speedup 1.0000x reference)
//
#include <hip/hip_runtime.h>
#include <hip/hip_bf16.h>
#include <cstdint>

typedef __attribute__((ext_vector_type(8))) short bf16x8;
typedef __attribute__((ext_vector_type(4))) float f32x4;

#define H_DIM 1024
#define B_DIM 32
#define L_DIM 2048
#define NT 32                   // K-tiles of 64 (K_TOT = 2048)

__device__ __forceinline__ void gload16(const void* g, void* l) {
  __builtin_amdgcn_global_load_lds(
      (const __attribute__((address_space(1))) unsigned int*)g,
      (__attribute__((address_space(3))) unsigned int*)l, 16, 0, 0);
}

#define VMCNT(n) asm volatile("s_waitcnt vmcnt(" #n ")" ::: "memory")
#define LGKM0 asm volatile("s_waitcnt lgkmcnt(0)" ::: "memory")
#define SBAR __builtin_amdgcn_sched_barrier(0)
#define BAR do { SBAR; __builtin_amdgcn_s_barrier(); SBAR; } while (0)

// fast tanh: 1 - 2/(exp(2x)+1). Saturates correctly; no NaN. Validated R12.
__device__ __forceinline__ float tanh_fast(float x) {
  return 1.f - 2.f / (__expf(2.f * x) + 1.f);
}

// 8x f32 -> bf16x8 (RNE, identical rounding to the old convert_all pass)
__device__ __forceinline__ bf16x8 pack8(float4 a, float4 b) {
  union { __hip_bfloat16 h; short s; } u;
  bf16x8 v;
  u.h = __float2bfloat16(a.x); v[0] = u.s;
  u.h = __float2bfloat16(a.y); v[1] = u.s;
  u.h = __float2bfloat16(a.z); v[2] = u.s;
  u.h = __float2bfloat16(a.w); v[3] = u.s;
  u.h = __float2bfloat16(b.x); v[4] = u.s;
  u.h = __float2bfloat16(b.y); v[5] = u.s;
  u.h = __float2bfloat16(b.z); v[6] = u.s;
  u.h = __float2bfloat16(b.w); v[7] = u.s;
  return v;
}

// ---------------------------------------------------------------- weights-only convert (8 MB traffic, ~3 us)
__global__ void __launch_bounds__(256)
convert_w(const float* __restrict__ Wk, const float* __restrict__ Wq,
          __hip_bfloat16* __restrict__ wkb, __hip_bfloat16* __restrict__ wqb) {
  const int i = blockIdx.x * 256 + threadIdx.x;   // 0..524287 float4 chunks
  const float* src = (i < 262144) ? Wk : Wq;
  __hip_bfloat16* dst = (i < 262144) ? wkb : wqb;
  const int off = i & 262143;
  float4 v = ((const float4*)src)[off];
  __hip_bfloat16 h[4];
  h[0] = __float2bfloat16(v.x);
  h[1] = __float2bfloat16(v.y);
  h[2] = __float2bfloat16(v.z);
  h[3] = __float2bfloat16(v.w);
  *(uint2*)(dst + (size_t)off * 4) = *(const uint2*)h;
}

// ---------------------------------------------------------------- 256x256x64 8-wave GEMM (R15: R14 + fixed prologue)
// R2 BUG: prologue issued A(1,kk0) into ra[0..3] BEFORE WRITE_A(0,0) consumed
// them -> tile 0 kk0 got tile 1 data (deterministic corruption, absmax 4e-2).
// Fixed order: WRITE_A(0,0) ; ISSUE_A(0,1) ; WRITE_A(1,0).
// Schedule (distance-2 prefetch, single 32-VGPR A buffer):
//   A(t+1,kk0): issued P4 of t-1, ds_write at P2 of t.
//   A(t+1,kk1): issued P2 of t,  ds_write at P4 of t.
// VMEM queue/tile: P2 = B(t+1,kk0)x2 + A(t+1,kk1)x4; P4 = B(t+1,kk1)x2 +
// A(t+2,kk0)x4. WRITE_A dep-drain (vmcnt<=2) hits only loads issued >=1.3
// phases earlier and subsumes all B-visibility deadlines; VMCNT(6) never
// drains to 0 mid-loop. Tail: PEN drops P4 issue (VMCNT(2)); LAST drains
// VMCNT(0)@P2. WAR: staged regions' readers finished >=2 barriers earlier.
// LDS (128 KiB): A parity p at p*32768 (two 16KB halves [kk][256r][32c] bf16,
// 64B rows); B at 65536 + p*32768. Swizzle: byte ^= ((byte>>7)&3)<<4 — applied
// on ds_write DEST for A (conflict-free: permutes 16B chunks within 128B
// windows), on global SOURCE for B (gload_lds dest stays linear).
__global__ void __launch_bounds__(512, 2)
gemm_score_kernel(const float* __restrict__ key,
                  const float* __restrict__ query,
                  const __hip_bfloat16* __restrict__ wkb,
                  const __hip_bfloat16* __restrict__ wqb,
                  const float* __restrict__ bias,
                  const float* __restrict__ w_score,
                  float* __restrict__ spart) {
  extern __shared__ __align__(1024) char lds[];

  // bijective XCD swizzle: nwg=1024 (%8==0), chunk=128
  const int d = blockIdx.x;
  const int orig = (d & 7) * 128 + (d >> 3);
  const int mt = orig >> 2;  // 0..255
  const int nt = orig & 3;   // 0..3

  const int tid = threadIdx.x;
  const int lane = tid & 63;
  const int w = tid >> 6;
  const int wr = w >> 2;     // 0..1
  const int wc = w & 3;      // 0..3

  // ---- staging precompute: per 16KB half, per thread 2 chunks of 16B (bf16).
  // B: linear LDS dest + pre-swizzled bf16 global source (gload_lds).
  // A: swizzled LDS dest + linear f32 global source (reg-staged, 32B/thread).
  int dstA[2], dstB[2];
  size_t asrcg[2], boffg[2];
#pragma unroll
  for (int i = 0; i < 2; ++i) {
    int p = (i * 512 + tid) * 16;
    int row = p >> 6;                       // 0..255
    int q = p ^ (((p >> 7) & 3) << 4);
    dstB[i] = p;
    boffg[i] = (size_t)(nt * 256 + row) * 1024 + ((q & 63) >> 1);
    dstA[i] = q;
    asrcg[i] = (size_t)(mt * 256 + row) * 1024 + ((p & 63) >> 1);
  }

  float4 ra[8];   // single A-stage buffer: [4*kk + j], 32 VGPR

#define ISSUE_A(kk, tt) do {                                                   \
    const float* sp_ = ((tt) * 64 < 1024) ? key : query;                       \
    const int kb_ = (((tt) * 64) & 1023) + (kk) * 32;                          \
    _Pragma("unroll") for (int i = 0; i < 2; ++i) {                            \
      const float* s0_ = sp_ + asrcg[i] + kb_;                                 \
      ra[4 * (kk) + 2 * i]     = *(const float4*)(s0_);                        \
      ra[4 * (kk) + 2 * i + 1] = *(const float4*)(s0_ + 4);                    \
    }                                                                          \
  } while (0)
#define WRITE_A(kk, tt) do {                                                   \
    char* db_ = lds + ((tt) & 1) * 32768 + (kk) * 16384;                       \
    _Pragma("unroll") for (int i = 0; i < 2; ++i)                              \
      *(bf16x8*)(db_ + dstA[i]) =                                              \
          pack8(ra[4 * (kk) + 2 * i], ra[4 * (kk) + 2 * i + 1]);               \
  } while (0)
#define STAGE_B(kk, tt) do {                                                   \
    const __hip_bfloat16* sp_ = ((tt) * 64 < 1024) ? wkb : wqb;                \
    const int kb_ = (((tt) * 64) & 1023) + (kk) * 32;                          \
    char* db_ = lds + 65536 + ((tt) & 1) * 32768 + (kk) * 16384;               \
    gload16(sp_ + boffg[0] + kb_, db_ + dstB[0]);                              \
    gload16(sp_ + boffg[1] + kb_, db_ + dstB[1]);                              \
  } while (0)

  // ---- fragment ds_read byte offsets (within parity base)
  const int frow = lane & 15;
  const int koffb = (lane >> 4) * 16;
  int aoff[8][2], boff[4][2];
#pragma unroll
  for (int m = 0; m < 8; ++m) {
    int r = wr * 128 + m * 16 + frow;
#pragma unroll
    for (int kk = 0; kk < 2; ++kk) {
      int byte = r * 64 + koffb;
      aoff[m][kk] = kk * 16384 + (byte ^ (((byte >> 7) & 3) << 4));
    }
  }
#pragma unroll
  for (int n = 0; n < 4; ++n) {
    int r = wc * 64 + n * 16 + frow;
#pragma unroll
    for (int kk = 0; kk < 2; ++kk) {
      int byte = r * 64 + koffb;
      boff[n][kk] = 65536 + kk * 16384 + (byte ^ (((byte >> 7) & 3) << 4));
    }
  }

  f32x4 acc[8][4] = {};

  // ---- prologue: tile 0 into LDS; A(1,kk0) issued AFTER WRITE_A(0,0) has
  // consumed ra[0..3] (R2 bug fix). Ledger: WRITE_A(0,0) dep vmcnt<=8;
  // ISSUE_A(0,1) refills ra[0..3]; WRITE_A(1,0) dep vmcnt<=8; VMCNT(4) drains
  // B(0,*) leaving exactly [A(1,kk0)x4] in flight = steady-state invariant.
  ISSUE_A(0, 0);
  ISSUE_A(1, 0);
  STAGE_B(0, 0);
  STAGE_B(1, 0);
  WRITE_A(0, 0);            // dep vmcnt<=8 (reads A(0,kk0))
  ISSUE_A(0, 1);            // ra[0..3] now free
  WRITE_A(1, 0);            // dep vmcnt<=8 (reads A(0,kk1))
  VMCNT(4);                 // B(0,*) landed; A(1,kk0) stays in flight
  LGKM0;
  BAR;

#define TILE_STEP(T, DO_STG, DO_ISS4, W2, W4, DO_BAR4)                         \
  do {                                                                         \
    const int t_ = (T);                                                        \
    const char* Ab = lds + (t_ & 1) * 32768;                                   \
    bf16x8 a0[4], a1[4], b0[4], b1[4];                                         \
    /* P1: reads kk0 m0-3 + B kk0 ; BAR ; MFMA */                              \
    _Pragma("unroll") for (int m = 0; m < 4; ++m)                              \
        a0[m] = *(const bf16x8*)(Ab + aoff[m][0]);                             \
    _Pragma("unroll") for (int n = 0; n < 4; ++n)                              \
        b0[n] = *(const bf16x8*)(Ab + boff[n][0]);                             \
    BAR;                                                                       \
    __builtin_amdgcn_s_setprio(1);                                             \
    _Pragma("unroll") for (int m = 0; m < 4; ++m)                              \
      _Pragma("unroll") for (int n = 0; n < 4; ++n)                            \
        acc[m][n] = __builtin_amdgcn_mfma_f32_16x16x32_bf16(                   \
            a0[m], b0[n], acc[m][n], 0, 0, 0);                                 \
    __builtin_amdgcn_s_setprio(0);                                             \
    /* P2: reads kk0 m4-7 ; stage B-kk0(t+1) ; write A-kk0(t+1) ;             \
       issue A-kk1(t+1) ; wait ; BAR ; MFMA */                                 \
    _Pragma("unroll") for (int m = 0; m < 4; ++m)                              \
        a1[m] = *(const bf16x8*)(Ab + aoff[4 + m][0]);                         \
    if (DO_STG) {                                                              \
      STAGE_B(0, t_ + 1); WRITE_A(0, t_ + 1); ISSUE_A(1, t_ + 1);              \
      W2; LGKM0;                                                               \
    } else { W2; }                                                             \
    BAR;                                                                       \
    __builtin_amdgcn_s_setprio(1);                                             \
    _Pragma("unroll") for (int m = 0; m < 4; ++m)                              \
      _Pragma("unroll") for (int n = 0; n < 4; ++n)                            \
        acc[4 + m][n] = __builtin_amdgcn_mfma_f32_16x16x32_bf16(               \
            a1[m], b0[n], acc[4 + m][n], 0, 0, 0);                             \
    __builtin_amdgcn_s_setprio(0);                                             \
    /* P3: reads kk1 m0-3 + B kk1 ; BAR ; MFMA */                              \
    _Pragma("unroll") for (int m = 0; m < 4; ++m)                              \
        a0[m] = *(const bf16x8*)(Ab + aoff[m][1]);                             \
    _Pragma("unroll") for (int n = 0; n < 4; ++n)                              \
        b1[n] = *(const bf16x8*)(Ab + boff[n][1]);                             \
    BAR;                                                                       \
    __builtin_amdgcn_s_setprio(1);                                             \
    _Pragma("unroll") for (int m = 0; m < 4; ++m)                              \
      _Pragma("unroll") for (int n = 0; n < 4; ++n)                            \
        acc[m][n] = __builtin_amdgcn_mfma_f32_16x16x32_bf16(                   \
            a0[m], b1[n], acc[m][n], 0, 0, 0);                                 \
    __builtin_amdgcn_s_setprio(0);                                             \
    /* P4: reads kk1 m4-7 ; stage B-kk1(t+1) ; write A-kk1(t+1) ;             \
       issue A-kk0(t+2) ; wait ; BAR ; MFMA */                                 \
    _Pragma("unroll") for (int m = 0; m < 4; ++m)                              \
        a1[m] = *(const bf16x8*)(Ab + aoff[4 + m][1]);                         \
    if (DO_STG) {                                                              \
      STAGE_B(1, t_ + 1); WRITE_A(1, t_ + 1);                                  \
      if (DO_ISS4) { ISSUE_A(0, t_ + 2); }                                     \
      W4; LGKM0;                                                               \
    }                                                                          \
    if (DO_BAR4) { BAR; }                                                      \
    __builtin_amdgcn_s_setprio(1);                                             \
    _Pragma("unroll") for (int m = 0; m < 4; ++m)                              \
      _Pragma("unroll") for (int n = 0; n < 4; ++n)                            \
        acc[4 + m][n] = __builtin_amdgcn_mfma_f32_16x16x32_bf16(               \
            a1[m], b1[n], acc[4 + m][n], 0, 0, 0);                             \
    __builtin_amdgcn_s_setprio(0);                                             \
  } while (0)

#pragma unroll 1
  for (int t = 0; t < NT - 2; ++t)
    TILE_STEP(t, 1, 1, VMCNT(6), VMCNT(6), 1);
  TILE_STEP(NT - 2, 1, 0, VMCNT(6), VMCNT(2), 1);   // PEN: no A(NT) issue
  TILE_STEP(NT - 1, 0, 0, VMCNT(0), (void)0, 0);    // LAST: drain only

  // ---- epilogue: fast-tanh + w_score partial dot, reduce over n (lane&15)
  const int nbase = nt * 256 + wc * 64;
  float wj[4], bj[4];
#pragma unroll
  for (int j = 0; j < 4; ++j) {
    int n = nbase + j * 16 + frow;
    wj[j] = w_score[n];
    bj[j] = bias[n];
  }
  const int mbase = mt * 256 + wr * 128;
  const int pidx = nt * 4 + wc;
#pragma unroll
  for (int i = 0; i < 8; ++i) {
#pragma unroll
    for (int r = 0; r < 4; ++r) {
      float v = 0.f;
#pragma unroll
      for (int j = 0; j < 4; ++j) v += wj[j] * tanh_fast(acc[i][j][r] + bj[j]);
      v += __shfl_xor(v, 1);
      v += __shfl_xor(v, 2);
      v += __shfl_xor(v, 4);
      v += __shfl_xor(v, 8);
      if (frow == 0) {
        int m = mbase + i * 16 + (lane >> 4) * 4 + r;
        spart[(size_t)m * 16 + pidx] = v;
      }
    }
  }
#undef TILE_STEP
#undef STAGE_B
#undef WRITE_A
#undef ISSUE_A
}

// ---------------------------------------------------------------- softmax over L per batch
__global__ void __launch_bounds__(256)
softmax_kernel(const float* __restrict__ spart, const float* __restrict__ b_score_p,
               float* __restrict__ attn) {
  const int b = blockIdx.x;
  const int tid = threadIdx.x;
  const int lane = tid & 63;
  const int w = tid >> 6;
  const float bsc = b_score_p[0];
  __shared__ float red[8];
  float s[8];
  float lmax = -1e30f;
#pragma unroll
  for (int u = 0; u < 8; ++u) {
    const int l = u * 256 + tid;
    const float4* p = (const float4*)(spart + ((size_t)b * 2048 + l) * 16);
    float4 a = p[0], c = p[1], d2 = p[2], e2 = p[3];
    float sum = bsc + a.x + a.y + a.z + a.w + c.x + c.y + c.z + c.w +
                d2.x + d2.y + d2.z + d2.w + e2.x + e2.y + e2.z + e2.w;
    s[u] = sum;
    lmax = fmaxf(lmax, sum);
  }
#pragma unroll
  for (int m = 32; m >= 1; m >>= 1) lmax = fmaxf(lmax, __shfl_xor(lmax, m));
  if (lane == 0) red[w] = lmax;
  __syncthreads();
  const float gmax = fmaxf(fmaxf(red[0], red[1]), fmaxf(red[2], red[3]));
  float e[8];
  float lsum = 0.f;
#pragma unroll
  for (int u = 0; u < 8; ++u) {
    e[u] = expf(s[u] - gmax);
    lsum += e[u];
  }
#pragma unroll
  for (int m = 32; m >= 1; m >>= 1) lsum += __shfl_xor(lsum, m);
  if (lane == 0) red[4 + w] = lsum;
  __syncthreads();
  const float inv = 1.f / (red[4] + red[5] + red[6] + red[7]);
#pragma unroll
  for (int u = 0; u < 8; ++u) attn[(size_t)b * 2048 + u * 256 + tid] = e[u] * inv;
}

// ---------------------------------------------------------------- context (f32 key, 32B/lane loads)
__global__ void __launch_bounds__(256)
ctx_part_kernel(const float* __restrict__ key, const float* __restrict__ attn,
                float* __restrict__ pctx) {
  __shared__ float a_sh[64];
  const int lc = blockIdx.x;   // 0..31
  const int b = blockIdx.y;    // 0..31
  const int tid = threadIdx.x;
  if (tid < 64) a_sh[tid] = attn[(size_t)b * 2048 + lc * 64 + tid];
  __syncthreads();
  const int ro = tid >> 7;            // 0..1
  const int h0 = (tid & 127) * 8;
  float ax[8] = {};
  const float* base =
      key + ((size_t)b * 2048 + lc * 64 + ro) * 1024 + h0;
#pragma unroll 4
  for (int li = 0; li < 32; ++li) {
    float a = a_sh[li * 2 + ro];
    float4 v0 = *(const float4*)(base + (size_t)li * 2048);
    float4 v1 = *(const float4*)(base + (size_t)li * 2048 + 4);
    ax[0] += a * v0.x; ax[1] += a * v0.y; ax[2] += a * v0.z; ax[3] += a * v0.w;
    ax[4] += a * v1.x; ax[5] += a * v1.y; ax[6] += a * v1.z; ax[7] += a * v1.w;
  }
  float* out = pctx + (((size_t)b * 32 + lc) * 2 + ro) * 1024 + h0;
#pragma unroll
  for (int j = 0; j < 8; ++j) out[j] = ax[j];
}

__global__ void __launch_bounds__(256)
ctx_reduce_kernel(const float* __restrict__ pctx, float* __restrict__ ctx) {
  const int idx = blockIdx.x * 256 + threadIdx.x;  // 0..32767
  const int b = idx >> 10, h = idx & 1023;
  float s = 0.f;
#pragma unroll
  for (int q = 0; q < 64; ++q) s += pctx[((size_t)b * 64 + q) * 1024 + h];
  ctx[idx] = s;
}

// ---------------------------------------------------------------- launch
extern "C" void kernel_launch(void* const* d_in, const int* in_sizes, int n_in,
                              void* d_out, int out_size, void* d_ws, size_t ws_size,
                              hipStream_t stream) {
  const float* query = (const float*)d_in[0];
  const float* key = (const float*)d_in[1];
  const float* Wq = (const float*)d_in[2];
  const float* Wk = (const float*)d_in[3];
  const float* bias = (const float*)d_in[4];
  const float* w_score = (const float*)d_in[5];
  const float* b_score = (const float*)d_in[6];

  float* out_ctx = (float*)d_out;
  float* out_attn = out_ctx + 32768;

  char* ws = (char*)d_ws;
  __hip_bfloat16* wkb = (__hip_bfloat16*)ws;                    // 2 MiB
  __hip_bfloat16* wqb = (__hip_bfloat16*)(ws + 2097152);        // 2 MiB
  float* spart = (float*)(ws + 4194304);                        // 4 MiB
  float* pctx = (float*)(ws + 8388608);                         // 8 MiB

  hipFuncSetAttribute((const void*)gemm_score_kernel,
                      hipFuncAttributeMaxDynamicSharedMemorySize, 131072);

  convert_w<<<2048, 256, 0, stream>>>(Wk, Wq, wkb, wqb);

  gemm_score_kernel<<<1024, 512, 131072, stream>>>(key, query, wkb, wqb, bias,
                                                   w_score, spart);

  softmax_kernel<<<B_DIM, 256, 0, stream>>>(spart, b_score, out_attn);

  ctx_part_kernel<<<dim3(32, B_DIM), 256, 0, stream>>>(key, out_attn, pctx);
  ctx_reduce_kernel<<<128, 256, 0, stream>>>(pctx, out_ctx);
}

// Round 4
// 528.968 us; speedup vs baseline: 1.0653x; 1.0653x over previous
//
#include <hip/hip_runtime.h>
#include <hip/hip_bf16.h>
#include <cstdint>

typedef __attribute__((ext_vector_type(8))) short bf16x8;
typedef __attribute__((ext_vector_type(4))) float f32x4;

#define H_DIM 1024
#define B_DIM 32
#define L_DIM 2048
#define NT 32                   // K-tiles of 64 (K_TOT = 2048)

__device__ __forceinline__ void gload16(const void* g, void* l) {
  __builtin_amdgcn_global_load_lds(
      (const __attribute__((address_space(1))) unsigned int*)g,
      (__attribute__((address_space(3))) unsigned int*)l, 16, 0, 0);
}

#define VMCNT(n) asm volatile("s_waitcnt vmcnt(" #n ")" ::: "memory")
#define LGKM0 asm volatile("s_waitcnt lgkmcnt(0)" ::: "memory")
#define SBAR __builtin_amdgcn_sched_barrier(0)
#define BAR do { SBAR; __builtin_amdgcn_s_barrier(); SBAR; } while (0)

// fast tanh: 1 - 2/(exp(2x)+1). Saturates correctly; no NaN. Validated R12.
__device__ __forceinline__ float tanh_fast(float x) {
  return 1.f - 2.f / (__expf(2.f * x) + 1.f);
}

// 8x f32 -> bf16x8 (RNE, identical rounding to the old convert_all pass)
__device__ __forceinline__ bf16x8 pack8(float4 a, float4 b) {
  union { __hip_bfloat16 h; short s; } u;
  bf16x8 v;
  u.h = __float2bfloat16(a.x); v[0] = u.s;
  u.h = __float2bfloat16(a.y); v[1] = u.s;
  u.h = __float2bfloat16(a.z); v[2] = u.s;
  u.h = __float2bfloat16(a.w); v[3] = u.s;
  u.h = __float2bfloat16(b.x); v[4] = u.s;
  u.h = __float2bfloat16(b.y); v[5] = u.s;
  u.h = __float2bfloat16(b.z); v[6] = u.s;
  u.h = __float2bfloat16(b.w); v[7] = u.s;
  return v;
}

// ---------------------------------------------------------------- weights-only convert (8 MB traffic, ~3 us)
__global__ void __launch_bounds__(256)
convert_w(const float* __restrict__ Wk, const float* __restrict__ Wq,
          __hip_bfloat16* __restrict__ wkb, __hip_bfloat16* __restrict__ wqb) {
  const int i = blockIdx.x * 256 + threadIdx.x;   // 0..524287 float4 chunks
  const float* src = (i < 262144) ? Wk : Wq;
  __hip_bfloat16* dst = (i < 262144) ? wkb : wqb;
  const int off = i & 262143;
  float4 v = ((const float4*)src)[off];
  __hip_bfloat16 h[4];
  h[0] = __float2bfloat16(v.x);
  h[1] = __float2bfloat16(v.y);
  h[2] = __float2bfloat16(v.z);
  h[3] = __float2bfloat16(v.w);
  *(uint2*)(dst + (size_t)off * 4) = *(const uint2*)h;
}

// ---------------------------------------------------------------- 256x256x64 8-wave GEMM (R16: fused A, >=2-phase deadlines)
// R1/R3 failures diagnosed: R3's VMCNT(6) forced 1-phase retirement of the P2
// A-issue, and A-kk1 had a 1-phase REGISTER dep (issue P2 -> consume P4 same
// tile). All 8 waves (1 block/CU) stalled at every P2/P4. Fix: move issues so
// every deadline is >=2 phases with the same 32-VGPR buffer:
//   A(t+2,kk0): issue P3(t) -> WRITE_A at P2(t+1)   (dep distance 3 phases)
//   A(t+2,kk1): issue P4(t) (after WRITE_A(1,t+1) frees ra[4..7])
//                -> WRITE_A at P4(t+1)              (dep distance 4 phases)
// vmem queue per tile: P3: I0x4 ; P4: B1x2, I1x4 ; P2: B0x2.
// Dep waits (compiler-forced): WRITE_A(0)@P2 vmcnt<=6; WRITE_A(1)@P4 vmcnt<=4.
// Explicit: W2=VMCNT(6) forces {I0(t+1), B1(t)} retired (both >=2 phases old);
// W4=VMCNT(10) forces {B0(t+1)} retired (2 phases). Never drains mid-loop.
// sched_barrier(0) fences pin vmem group order so literal counts hold.
// Tail: t=NT-2: no issue, W4=VMCNT(2); t=NT-1: W2=VMCNT(0) drain.
// WAR: every LDS region's readers finished >=2 barriers before overwrite.
// LDS (128 KiB): A parity p at p*32768 (two 16KB halves [kk][256r][32c] bf16,
// 64B rows); B at 65536 + p*32768. Swizzle: byte ^= ((byte>>7)&3)<<4 — applied
// on ds_write DEST for A, on global SOURCE for B (gload_lds dest stays linear).
__global__ void __launch_bounds__(512, 2)
gemm_score_kernel(const float* __restrict__ key,
                  const float* __restrict__ query,
                  const __hip_bfloat16* __restrict__ wkb,
                  const __hip_bfloat16* __restrict__ wqb,
                  const float* __restrict__ bias,
                  const float* __restrict__ w_score,
                  float* __restrict__ spart) {
  extern __shared__ __align__(1024) char lds[];

  // bijective XCD swizzle: nwg=1024 (%8==0), chunk=128
  const int d = blockIdx.x;
  const int orig = (d & 7) * 128 + (d >> 3);
  const int mt = orig >> 2;  // 0..255
  const int nt = orig & 3;   // 0..3

  const int tid = threadIdx.x;
  const int lane = tid & 63;
  const int w = tid >> 6;
  const int wr = w >> 2;     // 0..1
  const int wc = w & 3;      // 0..3

  // ---- staging precompute: per 16KB half, per thread 2 chunks of 16B (bf16).
  // B: linear LDS dest + pre-swizzled bf16 global source (gload_lds).
  // A: swizzled LDS dest + linear f32 global source (reg-staged, 32B/thread).
  int dstA[2], dstB[2];
  size_t asrcg[2], boffg[2];
#pragma unroll
  for (int i = 0; i < 2; ++i) {
    int p = (i * 512 + tid) * 16;
    int row = p >> 6;                       // 0..255
    int q = p ^ (((p >> 7) & 3) << 4);
    dstB[i] = p;
    boffg[i] = (size_t)(nt * 256 + row) * 1024 + ((q & 63) >> 1);
    dstA[i] = q;
    asrcg[i] = (size_t)(mt * 256 + row) * 1024 + ((p & 63) >> 1);
  }

  float4 ra[8];   // single A-stage buffer: [4*kk + j], 32 VGPR

#define ISSUE_A(kk, tt) do {                                                   \
    const float* sp_ = ((tt) * 64 < 1024) ? key : query;                       \
    const int kb_ = (((tt) * 64) & 1023) + (kk) * 32;                          \
    _Pragma("unroll") for (int i = 0; i < 2; ++i) {                            \
      const float* s0_ = sp_ + asrcg[i] + kb_;                                 \
      ra[4 * (kk) + 2 * i]     = *(const float4*)(s0_);                        \
      ra[4 * (kk) + 2 * i + 1] = *(const float4*)(s0_ + 4);                    \
    }                                                                          \
  } while (0)
#define WRITE_A(kk, tt) do {                                                   \
    char* db_ = lds + ((tt) & 1) * 32768 + (kk) * 16384;                       \
    _Pragma("unroll") for (int i = 0; i < 2; ++i)                              \
      *(bf16x8*)(db_ + dstA[i]) =                                              \
          pack8(ra[4 * (kk) + 2 * i], ra[4 * (kk) + 2 * i + 1]);               \
  } while (0)
#define STAGE_B(kk, tt) do {                                                   \
    const __hip_bfloat16* sp_ = ((tt) * 64 < 1024) ? wkb : wqb;                \
    const int kb_ = (((tt) * 64) & 1023) + (kk) * 32;                          \
    char* db_ = lds + 65536 + ((tt) & 1) * 32768 + (kk) * 16384;               \
    gload16(sp_ + boffg[0] + kb_, db_ + dstB[0]);                              \
    gload16(sp_ + boffg[1] + kb_, db_ + dstB[1]);                              \
  } while (0)

  // ---- fragment ds_read byte offsets (within parity base)
  const int frow = lane & 15;
  const int koffb = (lane >> 4) * 16;
  int aoff[8][2], boff[4][2];
#pragma unroll
  for (int m = 0; m < 8; ++m) {
    int r = wr * 128 + m * 16 + frow;
#pragma unroll
    for (int kk = 0; kk < 2; ++kk) {
      int byte = r * 64 + koffb;
      aoff[m][kk] = kk * 16384 + (byte ^ (((byte >> 7) & 3) << 4));
    }
  }
#pragma unroll
  for (int n = 0; n < 4; ++n) {
    int r = wc * 64 + n * 16 + frow;
#pragma unroll
    for (int kk = 0; kk < 2; ++kk) {
      int byte = r * 64 + koffb;
      boff[n][kk] = 65536 + kk * 16384 + (byte ^ (((byte >> 7) & 3) << 4));
    }
  }

  f32x4 acc[8][4] = {};

  // ---- prologue. Establishes steady invariant entering P1(0): LDS holds
  // tile 0; ra = A(1); outstanding = [B1(0)x2, I0(1)x4, I1(1)x4] (10 ops;
  // oldest-6 retirement at P2(0)'s VMCNT(6) covers B1(0)+I0(1) exactly).
  ISSUE_A(0, 0); ISSUE_A(1, 0); SBAR;   // I(0) x8
  STAGE_B(0, 0); STAGE_B(1, 0); SBAR;   // B(0) x4
  WRITE_A(0, 0); SBAR;                  // dep vmcnt<=8 (reads I0(0))
  ISSUE_A(0, 1); SBAR;                  // ra[0..3] free -> I0(1) x4
  WRITE_A(1, 0); SBAR;                  // dep vmcnt<=8 (reads I1(0))
  ISSUE_A(1, 1); SBAR;                  // ra[4..7] free -> I1(1) x4
  VMCNT(10);                            // forces I(0)+B0(0) retired
  LGKM0;
  BAR;

#define TILE_STEP(T, DO_STG, DO_ISS, W2, W4, DO_BAR4)                          \
  do {                                                                         \
    const int t_ = (T);                                                        \
    const char* Ab = lds + (t_ & 1) * 32768;                                   \
    bf16x8 a0[4], a1[4], b0[4], b1[4];                                         \
    /* P1: reads kk0 m0-3 + B kk0 ; BAR ; MFMA */                              \
    _Pragma("unroll") for (int m = 0; m < 4; ++m)                              \
        a0[m] = *(const bf16x8*)(Ab + aoff[m][0]);                             \
    _Pragma("unroll") for (int n = 0; n < 4; ++n)                              \
        b0[n] = *(const bf16x8*)(Ab + boff[n][0]);                             \
    BAR;                                                                       \
    __builtin_amdgcn_s_setprio(1);                                             \
    _Pragma("unroll") for (int m = 0; m < 4; ++m)                              \
      _Pragma("unroll") for (int n = 0; n < 4; ++n)                            \
        acc[m][n] = __builtin_amdgcn_mfma_f32_16x16x32_bf16(                   \
            a0[m], b0[n], acc[m][n], 0, 0, 0);                                 \
    __builtin_amdgcn_s_setprio(0);                                             \
    /* P2: reads kk0 m4-7 ; stage B-kk0(t+1) ; write A-kk0(t+1) ; W2 ; BAR */  \
    _Pragma("unroll") for (int m = 0; m < 4; ++m)                              \
        a1[m] = *(const bf16x8*)(Ab + aoff[4 + m][0]);                         \
    if (DO_STG) {                                                              \
      SBAR; STAGE_B(0, t_ + 1); SBAR; WRITE_A(0, t_ + 1); SBAR;                \
      W2; LGKM0;                                                               \
    } else { W2; }                                                             \
    BAR;                                                                       \
    __builtin_amdgcn_s_setprio(1);                                             \
    _Pragma("unroll") for (int m = 0; m < 4; ++m)                              \
      _Pragma("unroll") for (int n = 0; n < 4; ++n)                            \
        acc[4 + m][n] = __builtin_amdgcn_mfma_f32_16x16x32_bf16(               \
            a1[m], b0[n], acc[4 + m][n], 0, 0, 0);                             \
    __builtin_amdgcn_s_setprio(0);                                             \
    /* P3: reads kk1 m0-3 + B kk1 ; issue A-kk0(t+2) ; BAR ; MFMA */           \
    _Pragma("unroll") for (int m = 0; m < 4; ++m)                              \
        a0[m] = *(const bf16x8*)(Ab + aoff[m][1]);                             \
    _Pragma("unroll") for (int n = 0; n < 4; ++n)                              \
        b1[n] = *(const bf16x8*)(Ab + boff[n][1]);                             \
    if (DO_ISS) { SBAR; ISSUE_A(0, t_ + 2); }                                  \
    BAR;                                                                       \
    __builtin_amdgcn_s_setprio(1);                                             \
    _Pragma("unroll") for (int m = 0; m < 4; ++m)                              \
      _Pragma("unroll") for (int n = 0; n < 4; ++n)                            \
        acc[m][n] = __builtin_amdgcn_mfma_f32_16x16x32_bf16(                   \
            a0[m], b1[n], acc[m][n], 0, 0, 0);                                 \
    __builtin_amdgcn_s_setprio(0);                                             \
    /* P4: reads kk1 m4-7 ; stage B-kk1(t+1) ; write A-kk1(t+1) ;             \
       issue A-kk1(t+2) ; W4 ; BAR ; MFMA */                                   \
    _Pragma("unroll") for (int m = 0; m < 4; ++m)                              \
        a1[m] = *(const bf16x8*)(Ab + aoff[4 + m][1]);                         \
    if (DO_STG) {                                                              \
      SBAR; STAGE_B(1, t_ + 1); SBAR; WRITE_A(1, t_ + 1); SBAR;                \
      if (DO_ISS) { ISSUE_A(1, t_ + 2); SBAR; }                                \
      W4; LGKM0;                                                               \
    }                                                                          \
    if (DO_BAR4) { BAR; }                                                      \
    __builtin_amdgcn_s_setprio(1);                                             \
    _Pragma("unroll") for (int m = 0; m < 4; ++m)                              \
      _Pragma("unroll") for (int n = 0; n < 4; ++n)                            \
        acc[4 + m][n] = __builtin_amdgcn_mfma_f32_16x16x32_bf16(               \
            a1[m], b1[n], acc[4 + m][n], 0, 0, 0);                             \
    __builtin_amdgcn_s_setprio(0);                                             \
  } while (0)

#pragma unroll 1
  for (int t = 0; t < NT - 2; ++t)
    TILE_STEP(t, 1, 1, VMCNT(6), VMCNT(10), 1);
  TILE_STEP(NT - 2, 1, 0, VMCNT(6), VMCNT(2), 1);   // PEN: stage NT-1, no issue
  TILE_STEP(NT - 1, 0, 0, VMCNT(0), (void)0, 0);    // LAST: drain only

  // ---- epilogue: fast-tanh + w_score partial dot, reduce over n (lane&15)
  const int nbase = nt * 256 + wc * 64;
  float wj[4], bj[4];
#pragma unroll
  for (int j = 0; j < 4; ++j) {
    int n = nbase + j * 16 + frow;
    wj[j] = w_score[n];
    bj[j] = bias[n];
  }
  const int mbase = mt * 256 + wr * 128;
  const int pidx = nt * 4 + wc;
#pragma unroll
  for (int i = 0; i < 8; ++i) {
#pragma unroll
    for (int r = 0; r < 4; ++r) {
      float v = 0.f;
#pragma unroll
      for (int j = 0; j < 4; ++j) v += wj[j] * tanh_fast(acc[i][j][r] + bj[j]);
      v += __shfl_xor(v, 1);
      v += __shfl_xor(v, 2);
      v += __shfl_xor(v, 4);
      v += __shfl_xor(v, 8);
      if (frow == 0) {
        int m = mbase + i * 16 + (lane >> 4) * 4 + r;
        spart[(size_t)m * 16 + pidx] = v;
      }
    }
  }
#undef TILE_STEP
#undef STAGE_B
#undef WRITE_A
#undef ISSUE_A
}

// ---------------------------------------------------------------- softmax over L per batch
__global__ void __launch_bounds__(256)
softmax_kernel(const float* __restrict__ spart, const float* __restrict__ b_score_p,
               float* __restrict__ attn) {
  const int b = blockIdx.x;
  const int tid = threadIdx.x;
  const int lane = tid & 63;
  const int w = tid >> 6;
  const float bsc = b_score_p[0];
  __shared__ float red[8];
  float s[8];
  float lmax = -1e30f;
#pragma unroll
  for (int u = 0; u < 8; ++u) {
    const int l = u * 256 + tid;
    const float4* p = (const float4*)(spart + ((size_t)b * 2048 + l) * 16);
    float4 a = p[0], c = p[1], d2 = p[2], e2 = p[3];
    float sum = bsc + a.x + a.y + a.z + a.w + c.x + c.y + c.z + c.w +
                d2.x + d2.y + d2.z + d2.w + e2.x + e2.y + e2.z + e2.w;
    s[u] = sum;
    lmax = fmaxf(lmax, sum);
  }
#pragma unroll
  for (int m = 32; m >= 1; m >>= 1) lmax = fmaxf(lmax, __shfl_xor(lmax, m));
  if (lane == 0) red[w] = lmax;
  __syncthreads();
  const float gmax = fmaxf(fmaxf(red[0], red[1]), fmaxf(red[2], red[3]));
  float e[8];
  float lsum = 0.f;
#pragma unroll
  for (int u = 0; u < 8; ++u) {
    e[u] = expf(s[u] - gmax);
    lsum += e[u];
  }
#pragma unroll
  for (int m = 32; m >= 1; m >>= 1) lsum += __shfl_xor(lsum, m);
  if (lane == 0) red[4 + w] = lsum;
  __syncthreads();
  const float inv = 1.f / (red[4] + red[5] + red[6] + red[7]);
#pragma unroll
  for (int u = 0; u < 8; ++u) attn[(size_t)b * 2048 + u * 256 + tid] = e[u] * inv;
}

// ---------------------------------------------------------------- context (f32 key, 32B/lane loads)
__global__ void __launch_bounds__(256)
ctx_part_kernel(const float* __restrict__ key, const float* __restrict__ attn,
                float* __restrict__ pctx) {
  __shared__ float a_sh[64];
  const int lc = blockIdx.x;   // 0..31
  const int b = blockIdx.y;    // 0..31
  const int tid = threadIdx.x;
  if (tid < 64) a_sh[tid] = attn[(size_t)b * 2048 + lc * 64 + tid];
  __syncthreads();
  const int ro = tid >> 7;            // 0..1
  const int h0 = (tid & 127) * 8;
  float ax[8] = {};
  const float* base =
      key + ((size_t)b * 2048 + lc * 64 + ro) * 1024 + h0;
#pragma unroll 4
  for (int li = 0; li < 32; ++li) {
    float a = a_sh[li * 2 + ro];
    float4 v0 = *(const float4*)(base + (size_t)li * 2048);
    float4 v1 = *(const float4*)(base + (size_t)li * 2048 + 4);
    ax[0] += a * v0.x; ax[1] += a * v0.y; ax[2] += a * v0.z; ax[3] += a * v0.w;
    ax[4] += a * v1.x; ax[5] += a * v1.y; ax[6] += a * v1.z; ax[7] += a * v1.w;
  }
  float* out = pctx + (((size_t)b * 32 + lc) * 2 + ro) * 1024 + h0;
#pragma unroll
  for (int j = 0; j < 8; ++j) out[j] = ax[j];
}

__global__ void __launch_bounds__(256)
ctx_reduce_kernel(const float* __restrict__ pctx, float* __restrict__ ctx) {
  const int idx = blockIdx.x * 256 + threadIdx.x;  // 0..32767
  const int b = idx >> 10, h = idx & 1023;
  float s = 0.f;
#pragma unroll
  for (int q = 0; q < 64; ++q) s += pctx[((size_t)b * 64 + q) * 1024 + h];
  ctx[idx] = s;
}

// ---------------------------------------------------------------- launch
extern "C" void kernel_launch(void* const* d_in, const int* in_sizes, int n_in,
                              void* d_out, int out_size, void* d_ws, size_t ws_size,
                              hipStream_t stream) {
  const float* query = (const float*)d_in[0];
  const float* key = (const float*)d_in[1];
  const float* Wq = (const float*)d_in[2];
  const float* Wk = (const float*)d_in[3];
  const float* bias = (const float*)d_in[4];
  const float* w_score = (const float*)d_in[5];
  const float* b_score = (const float*)d_in[6];

  float* out_ctx = (float*)d_out;
  float* out_attn = out_ctx + 32768;

  char* ws = (char*)d_ws;
  __hip_bfloat16* wkb = (__hip_bfloat16*)ws;                    // 2 MiB
  __hip_bfloat16* wqb = (__hip_bfloat16*)(ws + 2097152);        // 2 MiB
  float* spart = (float*)(ws + 4194304);                        // 4 MiB
  float* pctx = (float*)(ws + 8388608);                         // 8 MiB

  hipFuncSetAttribute((const void*)gemm_score_kernel,
                      hipFuncAttributeMaxDynamicSharedMemorySize, 131072);

  convert_w<<<2048, 256, 0, stream>>>(Wk, Wq, wkb, wqb);

  gemm_score_kernel<<<1024, 512, 131072, stream>>>(key, query, wkb, wqb, bias,
                                                   w_score, spart);

  softmax_kernel<<<B_DIM, 256, 0, stream>>>(spart, b_score, out_attn);

  ctx_part_kernel<<<dim3(32, B_DIM), 256, 0, stream>>>(key, out_attn, pctx);
  ctx_reduce_kernel<<<128, 256, 0, stream>>>(pctx, out_ctx);
}

// Round 5
// 473.656 us; speedup vs baseline: 1.1897x; 1.1168x over previous
//
#include <hip/hip_runtime.h>
#include <hip/hip_bf16.h>
#include <cstdint>

typedef __attribute__((ext_vector_type(8))) short bf16x8;
typedef __attribute__((ext_vector_type(4))) float f32x4;
typedef __attribute__((ext_vector_type(16))) float f32x16;

#define H_DIM 1024
#define B_DIM 32
#define L_DIM 2048
#define M_TOT (B_DIM * L_DIM)   // 65536
#define K_TOT (2 * H_DIM)       // 2048
#define NT 32                   // K-tiles of 64

__device__ __forceinline__ void gload16(const void* g, void* l) {
  __builtin_amdgcn_global_load_lds(
      (const __attribute__((address_space(1))) unsigned int*)g,
      (__attribute__((address_space(3))) unsigned int*)l, 16, 0, 0);
}

#define VMCNT(n) asm volatile("s_waitcnt vmcnt(" #n ")" ::: "memory")
#define SBAR __builtin_amdgcn_sched_barrier(0)
#define BAR do { SBAR; __builtin_amdgcn_s_barrier(); SBAR; } while (0)

// fast tanh: 1 - 2/(exp(2x)+1). Saturates correctly; no NaN. Validated R12.
__device__ __forceinline__ float tanh_fast(float x) {
  return 1.f - 2.f / (__expf(2.f * x) + 1.f);
}

// ---------------------------------------------------------------- fused convert
__global__ void __launch_bounds__(256)
convert_all(const float* __restrict__ key, const float* __restrict__ query,
            const float* __restrict__ Wk, const float* __restrict__ Wq,
            __hip_bfloat16* __restrict__ keyb, __hip_bfloat16* __restrict__ qryb,
            __hip_bfloat16* __restrict__ wkb, __hip_bfloat16* __restrict__ wqb) {
  const int stride = gridDim.x * blockDim.x;
  for (int i = blockIdx.x * blockDim.x + threadIdx.x; i < 34078720; i += stride) {
    const float* src;
    __hip_bfloat16* dst;
    int off;
    if (i < 16777216)      { src = key;   dst = keyb; off = i; }
    else if (i < 33554432) { src = query; dst = qryb; off = i - 16777216; }
    else if (i < 33816576) { src = Wk;    dst = wkb;  off = i - 33554432; }
    else                   { src = Wq;    dst = wqb;  off = i - 33816576; }
    float4 v = ((const float4*)src)[off];
    __hip_bfloat16 h[4];
    h[0] = __float2bfloat16(v.x);
    h[1] = __float2bfloat16(v.y);
    h[2] = __float2bfloat16(v.z);
    h[3] = __float2bfloat16(v.w);
    *(uint2*)(dst + (size_t)off * 4) = *(const uint2*)h;
  }
}

// ---------------------------------------------------------------- 256x256x64 8-wave GEMM (R17: R11 schedule + 32x32x16 MFMA)
// R11 schedule restored verbatim (proven 273 us / 46% MfmaUtil): one barrier
// per phase; stage schedule P1->AK0, P2->BK0, P3->AK1, P4->BK1 of tile t+1;
// vmcnt(4)@P2/P4, never 0 mid-loop. Only change vs R0: MFMA shape
// 16x16x32 -> 32x32x16 (denser pipe: 2495 vs 2176 TF ceiling; 8 instr/phase
// instead of 16). ds_read volume/pattern per phase unchanged (P1:8 P2:4
// P3:8 P4:4 b128); 32-row frag reads are chunk-balanced under the same
// swizzle (8 hits per 16B chunk over 64 lanes = inherent floor).
// Fragment layouts (HW-verified m74/m101): A/B: row|col=lane&31,
// k=(lane>>5)*8+j. C/D: col=lane&31, row=(reg&3)+8*(reg>>2)+4*(lane>>5).
// LDS (128 KiB): A parity p at p*32768 (two 16KB halves [kk][256r][32c] bf16,
// 64B rows); B at 65536 + p*32768. Swizzle: byte ^= ((byte>>7)&3)<<4.
__global__ void __launch_bounds__(512, 2)
gemm_score_kernel(const __hip_bfloat16* __restrict__ keyb,
                  const __hip_bfloat16* __restrict__ qryb,
                  const __hip_bfloat16* __restrict__ wkb,
                  const __hip_bfloat16* __restrict__ wqb,
                  const float* __restrict__ bias,
                  const float* __restrict__ w_score,
                  float* __restrict__ spart) {
  extern __shared__ __align__(1024) char lds[];

  // bijective XCD swizzle: nwg=1024 (%8==0), chunk=128
  const int d = blockIdx.x;
  const int orig = (d & 7) * 128 + (d >> 3);
  const int mt = orig >> 2;  // 0..255
  const int nt = orig & 3;   // 0..3

  const int tid = threadIdx.x;
  const int lane = tid & 63;
  const int w = tid >> 6;
  const int wr = w >> 2;     // 0..1
  const int wc = w & 3;      // 0..3

  // ---- staging precompute: 2 loads of 16B per thread per 16KB half.
  int dstoff[2];
  size_t aoffg[2], boffg[2];
#pragma unroll
  for (int i = 0; i < 2; ++i) {
    int p = (i * 512 + tid) * 16;
    int row = p >> 6;                       // 0..255
    int q = p ^ (((p >> 7) & 3) << 4);
    int col = (q & 63) >> 1;                // 0..31
    dstoff[i] = p;
    aoffg[i] = (size_t)(mt * 256 + row) * 1024 + col;
    boffg[i] = (size_t)(nt * 256 + row) * 1024 + col;
  }

#define STAGE_A(kk, tt) do {                                                   \
    const __hip_bfloat16* sp_ = ((tt) * 64 < 1024) ? keyb : qryb;              \
    const int kb_ = (((tt) * 64) & 1023) + (kk) * 32;                          \
    char* db_ = lds + ((tt) & 1) * 32768 + (kk) * 16384;                       \
    gload16(sp_ + aoffg[0] + kb_, db_ + dstoff[0]);                            \
    gload16(sp_ + aoffg[1] + kb_, db_ + dstoff[1]);                            \
  } while (0)
#define STAGE_B(kk, tt) do {                                                   \
    const __hip_bfloat16* sp_ = ((tt) * 64 < 1024) ? wkb : wqb;                \
    const int kb_ = (((tt) * 64) & 1023) + (kk) * 32;                          \
    char* db_ = lds + 65536 + ((tt) & 1) * 32768 + (kk) * 16384;               \
    gload16(sp_ + boffg[0] + kb_, db_ + dstoff[0]);                            \
    gload16(sp_ + boffg[1] + kb_, db_ + dstoff[1]);                            \
  } while (0)

  // ---- fragment ds_read byte offsets for 32x32x16 frags.
  // k4 = 0..3 indexes K-16-chunks within the K=64 tile; half = k4>>1.
  const int col32 = lane & 31;
  const int hi = lane >> 5;
  int aoff[4][4], boff[2][4];
#pragma unroll
  for (int mb = 0; mb < 4; ++mb) {
    int r = wr * 128 + mb * 32 + col32;
#pragma unroll
    for (int k4 = 0; k4 < 4; ++k4) {
      int byte = r * 64 + hi * 16 + (k4 & 1) * 32;
      aoff[mb][k4] = (k4 >> 1) * 16384 + (byte ^ (((byte >> 7) & 3) << 4));
    }
  }
#pragma unroll
  for (int nb = 0; nb < 2; ++nb) {
    int rn = wc * 64 + nb * 32 + col32;
#pragma unroll
    for (int k4 = 0; k4 < 4; ++k4) {
      int byte = rn * 64 + hi * 16 + (k4 & 1) * 32;
      boff[nb][k4] = 65536 + (k4 >> 1) * 16384 + (byte ^ (((byte >> 7) & 3) << 4));
    }
  }

  f32x16 acc[4][2] = {};

  // ---- prologue: stage all 4 halves of tile 0 (FIFO order = read order)
  STAGE_A(0, 0); STAGE_B(0, 0); STAGE_A(1, 0); STAGE_B(1, 0);
  VMCNT(4);          // AK0(0),BK0(0) landed; AK1(0),BK1(0) in flight
  BAR;

#define TILE_STEP(T, DO_S, W2, W4, DO_BAR4)                                    \
  do {                                                                         \
    const int t_ = (T);                                                        \
    const char* Ab = lds + (t_ & 1) * 32768;                                   \
    bf16x8 aA[2][2], aB[2][2], bb[2][2];                                       \
    /* P1: reads kk0: A mb0-1 + B nb0-1 (k4 0-1) ; stage AK0(t+1) ; BAR */     \
    _Pragma("unroll") for (int mb = 0; mb < 2; ++mb)                           \
      _Pragma("unroll") for (int j = 0; j < 2; ++j)                            \
        aA[mb][j] = *(const bf16x8*)(Ab + aoff[mb][j]);                        \
    _Pragma("unroll") for (int nb = 0; nb < 2; ++nb)                           \
      _Pragma("unroll") for (int j = 0; j < 2; ++j)                            \
        bb[nb][j] = *(const bf16x8*)(Ab + boff[nb][j]);                        \
    if (DO_S) { STAGE_A(0, t_ + 1); }                                          \
    BAR;                                                                       \
    __builtin_amdgcn_s_setprio(1);                                             \
    _Pragma("unroll") for (int mb = 0; mb < 2; ++mb)                           \
      _Pragma("unroll") for (int nb = 0; nb < 2; ++nb)                         \
        _Pragma("unroll") for (int j = 0; j < 2; ++j)                          \
          acc[mb][nb] = __builtin_amdgcn_mfma_f32_32x32x16_bf16(               \
              aA[mb][j], bb[nb][j], acc[mb][nb], 0, 0, 0);                     \
    __builtin_amdgcn_s_setprio(0);                                             \
    /* P2: reads kk0: A mb2-3 ; stage BK0(t+1) ; vmcnt ; BAR ; MFMA */         \
    _Pragma("unroll") for (int mb = 0; mb < 2; ++mb)                           \
      _Pragma("unroll") for (int j = 0; j < 2; ++j)                            \
        aB[mb][j] = *(const bf16x8*)(Ab + aoff[2 + mb][j]);                    \
    if (DO_S) { STAGE_B(0, t_ + 1); }                                          \
    W2;                                                                        \
    BAR;                                                                       \
    __builtin_amdgcn_s_setprio(1);                                             \
    _Pragma("unroll") for (int mb = 0; mb < 2; ++mb)                           \
      _Pragma("unroll") for (int nb = 0; nb < 2; ++nb)                         \
        _Pragma("unroll") for (int j = 0; j < 2; ++j)                          \
          acc[2 + mb][nb] = __builtin_amdgcn_mfma_f32_32x32x16_bf16(           \
              aB[mb][j], bb[nb][j], acc[2 + mb][nb], 0, 0, 0);                 \
    __builtin_amdgcn_s_setprio(0);                                             \
    /* P3: reads kk1: A mb0-1 + B nb0-1 (k4 2-3) ; stage AK1(t+1) ; BAR */     \
    _Pragma("unroll") for (int mb = 0; mb < 2; ++mb)                           \
      _Pragma("unroll") for (int j = 0; j < 2; ++j)                            \
        aA[mb][j] = *(const bf16x8*)(Ab + aoff[mb][2 + j]);                    \
    _Pragma("unroll") for (int nb = 0; nb < 2; ++nb)                           \
      _Pragma("unroll") for (int j = 0; j < 2; ++j)                            \
        bb[nb][j] = *(const bf16x8*)(Ab + boff[nb][2 + j]);                    \
    if (DO_S) { STAGE_A(1, t_ + 1); }                                          \
    BAR;                                                                       \
    __builtin_amdgcn_s_setprio(1);                                             \
    _Pragma("unroll") for (int mb = 0; mb < 2; ++mb)                           \
      _Pragma("unroll") for (int nb = 0; nb < 2; ++nb)                         \
        _Pragma("unroll") for (int j = 0; j < 2; ++j)                          \
          acc[mb][nb] = __builtin_amdgcn_mfma_f32_32x32x16_bf16(               \
              aA[mb][j], bb[nb][j], acc[mb][nb], 0, 0, 0);                     \
    __builtin_amdgcn_s_setprio(0);                                             \
    /* P4: reads kk1: A mb2-3 ; stage BK1(t+1) ; vmcnt ; BAR ; MFMA */         \
    _Pragma("unroll") for (int mb = 0; mb < 2; ++mb)                           \
      _Pragma("unroll") for (int j = 0; j < 2; ++j)                            \
        aB[mb][j] = *(const bf16x8*)(Ab + aoff[2 + mb][2 + j]);                \
    if (DO_S) { STAGE_B(1, t_ + 1); }                                          \
    W4;                                                                        \
    if (DO_BAR4) { BAR; }                                                      \
    __builtin_amdgcn_s_setprio(1);                                             \
    _Pragma("unroll") for (int mb = 0; mb < 2; ++mb)                           \
      _Pragma("unroll") for (int nb = 0; nb < 2; ++nb)                         \
        _Pragma("unroll") for (int j = 0; j < 2; ++j)                          \
          acc[2 + mb][nb] = __builtin_amdgcn_mfma_f32_32x32x16_bf16(           \
              aB[mb][j], bb[nb][j], acc[2 + mb][nb], 0, 0, 0);                 \
    __builtin_amdgcn_s_setprio(0);                                             \
  } while (0)

#pragma unroll 1
  for (int t = 0; t < NT - 1; ++t)
    TILE_STEP(t, true, VMCNT(4), VMCNT(4), true);
  TILE_STEP(NT - 1, false, VMCNT(0), (void)0, false);

  // ---- epilogue: fast-tanh + w_score partial dot, reduce over 32 cols
  // C/D layout: col=lane&31, row=(reg&3)+8*(reg>>2)+4*hi.
  const int nbase = nt * 256 + wc * 64;
  float wj[2], bj[2];
#pragma unroll
  for (int nb = 0; nb < 2; ++nb) {
    int n = nbase + nb * 32 + col32;
    wj[nb] = w_score[n];
    bj[nb] = bias[n];
  }
  const int mbase = mt * 256 + wr * 128;
  const int pidx = nt * 4 + wc;
#pragma unroll
  for (int mb = 0; mb < 4; ++mb) {
#pragma unroll
    for (int i = 0; i < 16; ++i) {
      float v = wj[0] * tanh_fast(acc[mb][0][i] + bj[0]) +
                wj[1] * tanh_fast(acc[mb][1][i] + bj[1]);
      v += __shfl_xor(v, 1);
      v += __shfl_xor(v, 2);
      v += __shfl_xor(v, 4);
      v += __shfl_xor(v, 8);
      v += __shfl_xor(v, 16);
      if (col32 == 0) {
        int m = mbase + mb * 32 + (i & 3) + 8 * (i >> 2) + 4 * hi;
        spart[(size_t)m * 16 + pidx] = v;
      }
    }
  }
#undef TILE_STEP
#undef STAGE_A
#undef STAGE_B
}

// ---------------------------------------------------------------- softmax over L per batch
__global__ void __launch_bounds__(256)
softmax_kernel(const float* __restrict__ spart, const float* __restrict__ b_score_p,
               float* __restrict__ attn) {
  const int b = blockIdx.x;
  const int tid = threadIdx.x;
  const int lane = tid & 63;
  const int w = tid >> 6;
  const float bsc = b_score_p[0];
  __shared__ float red[8];
  float s[8];
  float lmax = -1e30f;
#pragma unroll
  for (int u = 0; u < 8; ++u) {
    const int l = u * 256 + tid;
    const float4* p = (const float4*)(spart + ((size_t)b * 2048 + l) * 16);
    float4 a = p[0], c = p[1], d2 = p[2], e2 = p[3];
    float sum = bsc + a.x + a.y + a.z + a.w + c.x + c.y + c.z + c.w +
                d2.x + d2.y + d2.z + d2.w + e2.x + e2.y + e2.z + e2.w;
    s[u] = sum;
    lmax = fmaxf(lmax, sum);
  }
#pragma unroll
  for (int m = 32; m >= 1; m >>= 1) lmax = fmaxf(lmax, __shfl_xor(lmax, m));
  if (lane == 0) red[w] = lmax;
  __syncthreads();
  const float gmax = fmaxf(fmaxf(red[0], red[1]), fmaxf(red[2], red[3]));
  float e[8];
  float lsum = 0.f;
#pragma unroll
  for (int u = 0; u < 8; ++u) {
    e[u] = expf(s[u] - gmax);
    lsum += e[u];
  }
#pragma unroll
  for (int m = 32; m >= 1; m >>= 1) lsum += __shfl_xor(lsum, m);
  if (lane == 0) red[4 + w] = lsum;
  __syncthreads();
  const float inv = 1.f / (red[4] + red[5] + red[6] + red[7]);
#pragma unroll
  for (int u = 0; u < 8; ++u) attn[(size_t)b * 2048 + u * 256 + tid] = e[u] * inv;
}

// ---------------------------------------------------------------- context (bf16 key, 16B/lane loads)
__global__ void __launch_bounds__(256)
ctx_part_kernel(const __hip_bfloat16* __restrict__ keyb, const float* __restrict__ attn,
                float* __restrict__ pctx) {
  __shared__ float a_sh[256];
  const int lc = blockIdx.x;   // 0..7
  const int b = blockIdx.y;    // 0..31
  const int tid = threadIdx.x;
  a_sh[tid] = attn[(size_t)b * 2048 + lc * 256 + tid];
  __syncthreads();
  const int ro = tid >> 7;            // 0..1
  const int h0 = (tid & 127) * 8;
  float ax[8] = {};
  const __hip_bfloat16* base =
      keyb + ((size_t)b * 2048 + lc * 256 + ro) * 1024 + h0;
#pragma unroll 4
  for (int li = 0; li < 128; ++li) {
    float a = a_sh[li * 2 + ro];
    bf16x8 kv = *(const bf16x8*)(base + (size_t)li * 2048);
#pragma unroll
    for (int j = 0; j < 8; ++j) {
      unsigned uv = ((unsigned)(unsigned short)kv[j]) << 16;
      ax[j] += a * __uint_as_float(uv);
    }
  }
  float* out = pctx + (((size_t)b * 8 + lc) * 2 + ro) * 1024 + h0;
#pragma unroll
  for (int j = 0; j < 8; ++j) out[j] = ax[j];
}

__global__ void __launch_bounds__(256)
ctx_reduce_kernel(const float* __restrict__ pctx, float* __restrict__ ctx) {
  const int idx = blockIdx.x * 256 + threadIdx.x;  // 0..32767
  const int b = idx >> 10, h = idx & 1023;
  float s = 0.f;
#pragma unroll
  for (int q = 0; q < 16; ++q) s += pctx[((size_t)b * 16 + q) * 1024 + h];
  ctx[idx] = s;
}

// ---------------------------------------------------------------- launch
extern "C" void kernel_launch(void* const* d_in, const int* in_sizes, int n_in,
                              void* d_out, int out_size, void* d_ws, size_t ws_size,
                              hipStream_t stream) {
  const float* query = (const float*)d_in[0];
  const float* key = (const float*)d_in[1];
  const float* Wq = (const float*)d_in[2];
  const float* Wk = (const float*)d_in[3];
  const float* bias = (const float*)d_in[4];
  const float* w_score = (const float*)d_in[5];
  const float* b_score = (const float*)d_in[6];

  float* out_ctx = (float*)d_out;
  float* out_attn = out_ctx + 32768;

  char* ws = (char*)d_ws;
  const size_t MB128 = 134217728;
  __hip_bfloat16* keyb = (__hip_bfloat16*)ws;
  __hip_bfloat16* qryb = (__hip_bfloat16*)(ws + MB128);
  __hip_bfloat16* wkb = (__hip_bfloat16*)(ws + 2 * MB128);
  __hip_bfloat16* wqb = (__hip_bfloat16*)(ws + 2 * MB128 + 2097152);
  float* spart = (float*)(ws + 2 * MB128 + 4194304);            // 4 MiB
  float* pctx = (float*)(ws + 2 * MB128 + 8388608);             // 2 MiB

  hipFuncSetAttribute((const void*)gemm_score_kernel,
                      hipFuncAttributeMaxDynamicSharedMemorySize, 131072);

  convert_all<<<16384, 256, 0, stream>>>(key, query, Wk, Wq, keyb, qryb, wkb, wqb);

  gemm_score_kernel<<<1024, 512, 131072, stream>>>(keyb, qryb, wkb, wqb, bias,
                                                   w_score, spart);

  softmax_kernel<<<B_DIM, 256, 0, stream>>>(spart, b_score, out_attn);

  ctx_part_kernel<<<dim3(8, B_DIM), 256, 0, stream>>>(keyb, out_attn, pctx);
  ctx_reduce_kernel<<<128, 256, 0, stream>>>(pctx, out_ctx);
}

// Round 6
// 439.036 us; speedup vs baseline: 1.2835x; 1.0789x over previous
//
#include <hip/hip_runtime.h>
#include <hip/hip_bf16.h>
#include <cstdint>

typedef __attribute__((ext_vector_type(8))) short bf16x8;
typedef __attribute__((ext_vector_type(4))) float f32x4;

#define H_DIM 1024
#define B_DIM 32
#define L_DIM 2048
#define M_TOT (B_DIM * L_DIM)   // 65536
#define K_TOT (2 * H_DIM)       // 2048
#define NT 32                   // K-tiles of 64

__device__ __forceinline__ void gload16(const void* g, void* l) {
  __builtin_amdgcn_global_load_lds(
      (const __attribute__((address_space(1))) unsigned int*)g,
      (__attribute__((address_space(3))) unsigned int*)l, 16, 0, 0);
}

#define VMCNT(n) asm volatile("s_waitcnt vmcnt(" #n ")" ::: "memory")
#define SBAR __builtin_amdgcn_sched_barrier(0)
#define BAR do { SBAR; __builtin_amdgcn_s_barrier(); SBAR; } while (0)

// fast tanh: 1 - 2/(exp(2x)+1). Saturates correctly; no NaN. Validated R12.
__device__ __forceinline__ float tanh_fast(float x) {
  return 1.f - 2.f / (__expf(2.f * x) + 1.f);
}

// ---------------------------------------------------------------- fused convert
__global__ void __launch_bounds__(256)
convert_all(const float* __restrict__ key, const float* __restrict__ query,
            const float* __restrict__ Wk, const float* __restrict__ Wq,
            __hip_bfloat16* __restrict__ keyb, __hip_bfloat16* __restrict__ qryb,
            __hip_bfloat16* __restrict__ wkb, __hip_bfloat16* __restrict__ wqb) {
  const int stride = gridDim.x * blockDim.x;
  for (int i = blockIdx.x * blockDim.x + threadIdx.x; i < 34078720; i += stride) {
    const float* src;
    __hip_bfloat16* dst;
    int off;
    if (i < 16777216)      { src = key;   dst = keyb; off = i; }
    else if (i < 33554432) { src = query; dst = qryb; off = i - 16777216; }
    else if (i < 33816576) { src = Wk;    dst = wkb;  off = i - 33554432; }
    else                   { src = Wq;    dst = wqb;  off = i - 33816576; }
    float4 v = ((const float4*)src)[off];
    __hip_bfloat16 h[4];
    h[0] = __float2bfloat16(v.x);
    h[1] = __float2bfloat16(v.y);
    h[2] = __float2bfloat16(v.z);
    h[3] = __float2bfloat16(v.w);
    *(uint2*)(dst + (size_t)off * 4) = *(const uint2*)h;
  }
}

// ---------------------------------------------------------------- 256x256x64 8-wave GEMM (R11 schedule, best measured)
// One barrier per phase: [reads][stage][wait?][BAR][MFMA] -- no barrier after
// MFMA, so the next phase's ds_reads issue behind this wave's MFMA cluster and
// other waves' reads fill the LDS pipe DURING the MFMA window. 1-phase skew.
// Stage schedule (tile t stages t+1): P1->AK0, P2->BK0, P3->AK1, P4->BK1.
// vmcnt(4)@P2 drains AK1,BK1(t) (staged P3/P4 of t-1, read by P3/P4 of t);
// vmcnt(4)@P4 drains AK0,BK0(t+1) (read by P1/P2 of t+1). Never 0 mid-loop.
// WAR: stage target's readers completed >=1 barrier before the stage issue.
// LDS (128 KiB): A parity p at p*32768 (two 16KB halves [kk][256r][32c] bf16,
// 64B rows); B at 65536 + p*32768. Swizzle: byte ^= ((byte>>7)&3)<<4.
// NOTE (R5 lesson): this swizzle is conflict-free ONLY for the 16x16 fragment
// pattern (16 rows x 4 chunk-cols/wave). 32x32 frags (32 rows x 1 chunk-col)
// alias every 8 rows -> 4-way conflicts (measured 2.5e7). Keep 16x16x32.
__global__ void __launch_bounds__(512, 2)
gemm_score_kernel(const __hip_bfloat16* __restrict__ keyb,
                  const __hip_bfloat16* __restrict__ qryb,
                  const __hip_bfloat16* __restrict__ wkb,
                  const __hip_bfloat16* __restrict__ wqb,
                  const float* __restrict__ bias,
                  const float* __restrict__ w_score,
                  float* __restrict__ spart) {
  extern __shared__ __align__(1024) char lds[];

  // bijective XCD swizzle: nwg=1024 (%8==0), chunk=128
  const int d = blockIdx.x;
  const int orig = (d & 7) * 128 + (d >> 3);
  const int mt = orig >> 2;  // 0..255
  const int nt = orig & 3;   // 0..3

  const int tid = threadIdx.x;
  const int lane = tid & 63;
  const int w = tid >> 6;
  const int wr = w >> 2;     // 0..1
  const int wc = w & 3;      // 0..3

  // ---- staging precompute: 2 loads of 16B per thread per 16KB half.
  int dstoff[2];
  size_t aoffg[2], boffg[2];
#pragma unroll
  for (int i = 0; i < 2; ++i) {
    int p = (i * 512 + tid) * 16;
    int row = p >> 6;                       // 0..255
    int q = p ^ (((p >> 7) & 3) << 4);
    int col = (q & 63) >> 1;                // 0..31
    dstoff[i] = p;
    aoffg[i] = (size_t)(mt * 256 + row) * 1024 + col;
    boffg[i] = (size_t)(nt * 256 + row) * 1024 + col;
  }

#define STAGE_A(kk, tt) do {                                                   \
    const __hip_bfloat16* sp_ = ((tt) * 64 < 1024) ? keyb : qryb;              \
    const int kb_ = (((tt) * 64) & 1023) + (kk) * 32;                          \
    char* db_ = lds + ((tt) & 1) * 32768 + (kk) * 16384;                       \
    gload16(sp_ + aoffg[0] + kb_, db_ + dstoff[0]);                            \
    gload16(sp_ + aoffg[1] + kb_, db_ + dstoff[1]);                            \
  } while (0)
#define STAGE_B(kk, tt) do {                                                   \
    const __hip_bfloat16* sp_ = ((tt) * 64 < 1024) ? wkb : wqb;                \
    const int kb_ = (((tt) * 64) & 1023) + (kk) * 32;                          \
    char* db_ = lds + 65536 + ((tt) & 1) * 32768 + (kk) * 16384;               \
    gload16(sp_ + boffg[0] + kb_, db_ + dstoff[0]);                            \
    gload16(sp_ + boffg[1] + kb_, db_ + dstoff[1]);                            \
  } while (0)

  // ---- fragment ds_read byte offsets (within parity base)
  const int frow = lane & 15;
  const int koffb = (lane >> 4) * 16;
  int aoff[8][2], boff[4][2];
#pragma unroll
  for (int m = 0; m < 8; ++m) {
    int r = wr * 128 + m * 16 + frow;
#pragma unroll
    for (int kk = 0; kk < 2; ++kk) {
      int byte = r * 64 + koffb;
      aoff[m][kk] = kk * 16384 + (byte ^ (((byte >> 7) & 3) << 4));
    }
  }
#pragma unroll
  for (int n = 0; n < 4; ++n) {
    int r = wc * 64 + n * 16 + frow;
#pragma unroll
    for (int kk = 0; kk < 2; ++kk) {
      int byte = r * 64 + koffb;
      boff[n][kk] = 65536 + kk * 16384 + (byte ^ (((byte >> 7) & 3) << 4));
    }
  }

  f32x4 acc[8][4] = {};

  // ---- prologue: stage all 4 halves of tile 0 (FIFO order = read order)
  STAGE_A(0, 0); STAGE_B(0, 0); STAGE_A(1, 0); STAGE_B(1, 0);
  VMCNT(4);          // AK0(0),BK0(0) landed; AK1(0),BK1(0) in flight
  BAR;

#define TILE_STEP(T, DO_S, W2, W4, DO_BAR4)                                    \
  do {                                                                         \
    const int t_ = (T);                                                        \
    const char* Ab = lds + (t_ & 1) * 32768;                                   \
    bf16x8 a0[4], a1[4], b0[4], b1[4];                                         \
    /* P1: reads kk0 m0-3 + B kk0 ; stage AK0(t+1) ; BAR ; MFMA */             \
    _Pragma("unroll") for (int m = 0; m < 4; ++m)                              \
        a0[m] = *(const bf16x8*)(Ab + aoff[m][0]);                             \
    _Pragma("unroll") for (int n = 0; n < 4; ++n)                              \
        b0[n] = *(const bf16x8*)(Ab + boff[n][0]);                             \
    if (DO_S) { STAGE_A(0, t_ + 1); }                                          \
    BAR;                                                                       \
    __builtin_amdgcn_s_setprio(1);                                             \
    _Pragma("unroll") for (int m = 0; m < 4; ++m)                              \
      _Pragma("unroll") for (int n = 0; n < 4; ++n)                            \
        acc[m][n] = __builtin_amdgcn_mfma_f32_16x16x32_bf16(                   \
            a0[m], b0[n], acc[m][n], 0, 0, 0);                                 \
    __builtin_amdgcn_s_setprio(0);                                             \
    /* P2: reads kk0 m4-7 ; stage BK0(t+1) ; vmcnt ; BAR ; MFMA */             \
    _Pragma("unroll") for (int m = 0; m < 4; ++m)                              \
        a1[m] = *(const bf16x8*)(Ab + aoff[4 + m][0]);                         \
    if (DO_S) { STAGE_B(0, t_ + 1); }                                          \
    W2;                                                                        \
    BAR;                                                                       \
    __builtin_amdgcn_s_setprio(1);                                             \
    _Pragma("unroll") for (int m = 0; m < 4; ++m)                              \
      _Pragma("unroll") for (int n = 0; n < 4; ++n)                            \
        acc[4 + m][n] = __builtin_amdgcn_mfma_f32_16x16x32_bf16(               \
            a1[m], b0[n], acc[4 + m][n], 0, 0, 0);                             \
    __builtin_amdgcn_s_setprio(0);                                             \
    /* P3: reads kk1 m0-3 + B kk1 ; stage AK1(t+1) ; BAR ; MFMA */             \
    _Pragma("unroll") for (int m = 0; m < 4; ++m)                              \
        a0[m] = *(const bf16x8*)(Ab + aoff[m][1]);                             \
    _Pragma("unroll") for (int n = 0; n < 4; ++n)                              \
        b1[n] = *(const bf16x8*)(Ab + boff[n][1]);                             \
    if (DO_S) { STAGE_A(1, t_ + 1); }                                          \
    BAR;                                                                       \
    __builtin_amdgcn_s_setprio(1);                                             \
    _Pragma("unroll") for (int m = 0; m < 4; ++m)                              \
      _Pragma("unroll") for (int n = 0; n < 4; ++n)                            \
        acc[m][n] = __builtin_amdgcn_mfma_f32_16x16x32_bf16(                   \
            a0[m], b1[n], acc[m][n], 0, 0, 0);                                 \
    __builtin_amdgcn_s_setprio(0);                                             \
    /* P4: reads kk1 m4-7 ; stage BK1(t+1) ; vmcnt ; BAR ; MFMA */             \
    _Pragma("unroll") for (int m = 0; m < 4; ++m)                              \
        a1[m] = *(const bf16x8*)(Ab + aoff[4 + m][1]);                         \
    if (DO_S) { STAGE_B(1, t_ + 1); }                                          \
    W4;                                                                        \
    if (DO_BAR4) { BAR; }                                                      \
    __builtin_amdgcn_s_setprio(1);                                             \
    _Pragma("unroll") for (int m = 0; m < 4; ++m)                              \
      _Pragma("unroll") for (int n = 0; n < 4; ++n)                            \
        acc[4 + m][n] = __builtin_amdgcn_mfma_f32_16x16x32_bf16(               \
            a1[m], b1[n], acc[4 + m][n], 0, 0, 0);                             \
    __builtin_amdgcn_s_setprio(0);                                             \
  } while (0)

#pragma unroll 1
  for (int t = 0; t < NT - 1; ++t)
    TILE_STEP(t, true, VMCNT(4), VMCNT(4), true);
  TILE_STEP(NT - 1, false, VMCNT(0), (void)0, false);

  // ---- epilogue: fast-tanh + w_score partial dot, reduce over n (lane&15)
  const int nbase = nt * 256 + wc * 64;
  float wj[4], bj[4];
#pragma unroll
  for (int j = 0; j < 4; ++j) {
    int n = nbase + j * 16 + frow;
    wj[j] = w_score[n];
    bj[j] = bias[n];
  }
  const int mbase = mt * 256 + wr * 128;
  const int pidx = nt * 4 + wc;
#pragma unroll
  for (int i = 0; i < 8; ++i) {
#pragma unroll
    for (int r = 0; r < 4; ++r) {
      float v = 0.f;
#pragma unroll
      for (int j = 0; j < 4; ++j) v += wj[j] * tanh_fast(acc[i][j][r] + bj[j]);
      v += __shfl_xor(v, 1);
      v += __shfl_xor(v, 2);
      v += __shfl_xor(v, 4);
      v += __shfl_xor(v, 8);
      if (frow == 0) {
        int m = mbase + i * 16 + (lane >> 4) * 4 + r;
        spart[(size_t)m * 16 + pidx] = v;
      }
    }
  }
#undef TILE_STEP
#undef STAGE_A
#undef STAGE_B
}

// ---------------------------------------------------------------- softmax over L per batch
__global__ void __launch_bounds__(256)
softmax_kernel(const float* __restrict__ spart, const float* __restrict__ b_score_p,
               float* __restrict__ attn) {
  const int b = blockIdx.x;
  const int tid = threadIdx.x;
  const int lane = tid & 63;
  const int w = tid >> 6;
  const float bsc = b_score_p[0];
  __shared__ float red[8];
  float s[8];
  float lmax = -1e30f;
#pragma unroll
  for (int u = 0; u < 8; ++u) {
    const int l = u * 256 + tid;
    const float4* p = (const float4*)(spart + ((size_t)b * 2048 + l) * 16);
    float4 a = p[0], c = p[1], d2 = p[2], e2 = p[3];
    float sum = bsc + a.x + a.y + a.z + a.w + c.x + c.y + c.z + c.w +
                d2.x + d2.y + d2.z + d2.w + e2.x + e2.y + e2.z + e2.w;
    s[u] = sum;
    lmax = fmaxf(lmax, sum);
  }
#pragma unroll
  for (int m = 32; m >= 1; m >>= 1) lmax = fmaxf(lmax, __shfl_xor(lmax, m));
  if (lane == 0) red[w] = lmax;
  __syncthreads();
  const float gmax = fmaxf(fmaxf(red[0], red[1]), fmaxf(red[2], red[3]));
  float e[8];
  float lsum = 0.f;
#pragma unroll
  for (int u = 0; u < 8; ++u) {
    e[u] = expf(s[u] - gmax);
    lsum += e[u];
  }
#pragma unroll
  for (int m = 32; m >= 1; m >>= 1) lsum += __shfl_xor(lsum, m);
  if (lane == 0) red[4 + w] = lsum;
  __syncthreads();
  const float inv = 1.f / (red[4] + red[5] + red[6] + red[7]);
#pragma unroll
  for (int u = 0; u < 8; ++u) attn[(size_t)b * 2048 + u * 256 + tid] = e[u] * inv;
}

// ---------------------------------------------------------------- context (bf16 key, 16B/lane loads)
// Block (lc, b): 256 l-rows x 1024 h. Thread (ro = tid>>7, h0 = (tid&127)*8)
// accumulates 8 h-values over its 128 l-rows (l = 2*li + ro). 16B/lane
// coalesced (128 lanes x 16B = one 2KB row). pctx slot per (lc, ro).
__global__ void __launch_bounds__(256)
ctx_part_kernel(const __hip_bfloat16* __restrict__ keyb, const float* __restrict__ attn,
                float* __restrict__ pctx) {
  __shared__ float a_sh[256];
  const int lc = blockIdx.x;   // 0..7
  const int b = blockIdx.y;    // 0..31
  const int tid = threadIdx.x;
  a_sh[tid] = attn[(size_t)b * 2048 + lc * 256 + tid];
  __syncthreads();
  const int ro = tid >> 7;            // 0..1
  const int h0 = (tid & 127) * 8;
  float ax[8] = {};
  const __hip_bfloat16* base =
      keyb + ((size_t)b * 2048 + lc * 256 + ro) * 1024 + h0;
#pragma unroll 4
  for (int li = 0; li < 128; ++li) {
    float a = a_sh[li * 2 + ro];
    bf16x8 kv = *(const bf16x8*)(base + (size_t)li * 2048);
#pragma unroll
    for (int j = 0; j < 8; ++j) {
      unsigned uv = ((unsigned)(unsigned short)kv[j]) << 16;
      ax[j] += a * __uint_as_float(uv);
    }
  }
  float* out = pctx + (((size_t)b * 8 + lc) * 2 + ro) * 1024 + h0;
#pragma unroll
  for (int j = 0; j < 8; ++j) out[j] = ax[j];
}

__global__ void __launch_bounds__(256)
ctx_reduce_kernel(const float* __restrict__ pctx, float* __restrict__ ctx) {
  const int idx = blockIdx.x * 256 + threadIdx.x;  // 0..32767
  const int b = idx >> 10, h = idx & 1023;
  float s = 0.f;
#pragma unroll
  for (int q = 0; q < 16; ++q) s += pctx[((size_t)b * 16 + q) * 1024 + h];
  ctx[idx] = s;
}

// ---------------------------------------------------------------- launch
extern "C" void kernel_launch(void* const* d_in, const int* in_sizes, int n_in,
                              void* d_out, int out_size, void* d_ws, size_t ws_size,
                              hipStream_t stream) {
  const float* query = (const float*)d_in[0];
  const float* key = (const float*)d_in[1];
  const float* Wq = (const float*)d_in[2];
  const float* Wk = (const float*)d_in[3];
  const float* bias = (const float*)d_in[4];
  const float* w_score = (const float*)d_in[5];
  const float* b_score = (const float*)d_in[6];

  float* out_ctx = (float*)d_out;
  float* out_attn = out_ctx + 32768;

  char* ws = (char*)d_ws;
  const size_t MB128 = 134217728;
  __hip_bfloat16* keyb = (__hip_bfloat16*)ws;
  __hip_bfloat16* qryb = (__hip_bfloat16*)(ws + MB128);
  __hip_bfloat16* wkb = (__hip_bfloat16*)(ws + 2 * MB128);
  __hip_bfloat16* wqb = (__hip_bfloat16*)(ws + 2 * MB128 + 2097152);
  float* spart = (float*)(ws + 2 * MB128 + 4194304);            // 4 MiB
  float* pctx = (float*)(ws + 2 * MB128 + 8388608);             // 2 MiB

  hipFuncSetAttribute((const void*)gemm_score_kernel,
                      hipFuncAttributeMaxDynamicSharedMemorySize, 131072);

  convert_all<<<16384, 256, 0, stream>>>(key, query, Wk, Wq, keyb, qryb, wkb, wqb);

  gemm_score_kernel<<<1024, 512, 131072, stream>>>(keyb, qryb, wkb, wqb, bias,
                                                   w_score, spart);

  softmax_kernel<<<B_DIM, 256, 0, stream>>>(spart, b_score, out_attn);

  ctx_part_kernel<<<dim3(8, B_DIM), 256, 0, stream>>>(keyb, out_attn, pctx);
  ctx_reduce_kernel<<<128, 256, 0, stream>>>(pctx, out_ctx);
}